// Round 6
// baseline (205.257 us; speedup 1.0000x reference)
//
#include <hip/hip_runtime.h>

#define NT     111
#define LMAX   5
#define TAU    32
#define NBATCH 32
#define ROW    2304   // f32 elements per batch row of fs
#define BPB    4      // batches per block (grid.y = NBATCH/BPB)

struct Tup { int l, l1, l2, out_off, in1, in2; };
struct Meta { Tup t[NT]; int totch; };

constexpr int IN_OFF[LMAX + 1] = {0, 64, 256, 576, 1024, 1600};

constexpr Meta make_meta() {
  Meta m{};
  int n = 0, out = 0;
  for (int l = 0; l <= LMAX; ++l)
    for (int l1 = 0; l1 <= LMAX; ++l1)
      for (int l2 = 0; l2 <= LMAX; ++l2) {
        int df = l1 - l2; if (df < 0) df = -df;
        if (df <= l && l <= l1 + l2) {
          m.t[n].l = l; m.t[n].l1 = l1; m.t[n].l2 = l2;
          m.t[n].out_off = out;
          m.t[n].in1 = IN_OFF[l1]; m.t[n].in2 = IN_OFF[l2];
          out += TAU * TAU * (2 * l + 1);
          ++n;
        }
      }
  m.totch = out;
  return m;
}

constexpr Meta META  = make_meta();
constexpr int  TOTCH = META.totch;   // 789504 complex pairs per batch

// ---------- compile-time CG coefficients ----------
constexpr double cfact(int n) { double r = 1.0; for (int i = 2; i <= n; ++i) r *= i; return r; }

constexpr double csqrt(double x) {
  if (x <= 0.0) return 0.0;
  double g = x;
  for (int i = 0; i < 100; ++i) g = 0.5 * (g + x / g);  // Newton, converges to f64 ulp
  return g;
}

// Condon-Shortley CG coefficient <j1 m1 j2 m2 | j3 m3>, Racah formula, f64 exact factorials.
constexpr double cg_coef_ct(int j1, int m1, int j2, int m2, int j3, int m3) {
  if (m1 + m2 != m3) return 0.0;
  double pref = csqrt((2.0 * j3 + 1.0) * cfact(j3 + j1 - j2) * cfact(j3 - j1 + j2) *
                      cfact(j1 + j2 - j3) / cfact(j1 + j2 + j3 + 1));
  pref *= csqrt(cfact(j3 + m3) * cfact(j3 - m3) * cfact(j1 - m1) * cfact(j1 + m1) *
                cfact(j2 - m2) * cfact(j2 + m2));
  double s = 0.0;
  const int kmax = j1 + j2 - j3;
  for (int k = 0; k <= kmax; ++k) {
    const int a3 = j1 - m1 - k, a4 = j2 + m2 - k, a5 = j3 - j2 + m1 + k, a6 = j3 - j1 - m2 + k;
    if (a3 < 0 || a4 < 0 || a5 < 0 || a6 < 0) continue;
    const double den = cfact(k) * cfact(kmax - k) * cfact(a3) * cfact(a4) * cfact(a5) * cfact(a6);
    s += ((k & 1) ? -1.0 : 1.0) / den;
  }
  return pref * s;
}

// Per-tuple constexpr table (separate variable per tuple keeps each constexpr
// evaluation ~100k steps, under clang's per-initializer limit).
template<int L, int L1, int L2>
struct CGTab {
  struct T { float v[2 * L + 1][2 * L1 + 1][2 * L2 + 1]; };
  static constexpr T gen() {
    T t{};
    for (int m = 0; m < 2 * L + 1; ++m)
      for (int i1 = 0; i1 < 2 * L1 + 1; ++i1)
        for (int i2 = 0; i2 < 2 * L2 + 1; ++i2)
          t.v[m][i1][i2] = (float)cg_coef_ct(L1, i1 - L1, L2, i2 - L2, L, m - L);
    return t;
  }
  static constexpr T tab = gen();
};

// ---------- per-tuple contraction ----------
// Round-6 change: each block processes BPB=4 batches (grid 111x8). The
// straight-line unrolled body (~3 KB/tuple, ~170 KB image total) is fetched
// cold from L2 once per block; reusing it for 4 batches x 4 j-iters amortizes
// the instruction-fetch cost 4x vs round-5 (theory: cold-I$ streaming is the
// dominant unmodeled ~40 us). Grid is now single-generation (~3.5 blocks/CU,
// ~10 KB hot code per CU -> I$-resident after warm-up).
//
// Store path unchanged from round 5 (wave-private LDS transpose, zero
// barriers, s_waitcnt lgkmcnt(0) fences only, float4 coalesced stores).
template<int L, int L1, int L2>
__device__ __forceinline__ void tuple_impl(const float* __restrict__ fs,
                                           float2* __restrict__ out,
                                           int in1, int in2, int out_off,
                                           float2* __restrict__ stage) {
  constexpr int D = 2 * L + 1, D1 = 2 * L1 + 1, D2 = 2 * L2 + 1;
  const int tid  = threadIdx.x;
  const int lane = tid & 63;
  const int wv   = tid >> 6;
  float2* swave = stage + wv * (64 * D);   // this wave's private slice
  const int t2 = tid & 31;

  #pragma unroll 1
  for (int bb = 0; bb < BPB; ++bb) {
    const int b = blockIdx.y * BPB + bb;
    const float* fa = fs + b * ROW + in1;
    const float* fb = fs + b * ROW + in2;
    float2* po = out + (size_t)b * TOTCH + out_off;

    float br[D2], bi[D2];
    const float2* pb = (const float2*)fb + t2 * D2;
    #pragma unroll
    for (int i = 0; i < D2; ++i) { float2 v = pb[i]; br[i] = v.x; bi[i] = v.y; }

    #pragma unroll 1
    for (int j = 0; j < 4; ++j) {
      const int tp = tid + 256 * j;
      const int t1 = tp >> 5;

      float ar[D1], ai[D1];
      const float2* pa = (const float2*)fa + t1 * D1;
      #pragma unroll
      for (int i = 0; i < D1; ++i) { float2 v = pa[i]; ar[i] = v.x; ai[i] = v.y; }

      float2 res[D];
      #pragma unroll
      for (int m = 0; m < D; ++m) {
        float re = 0.f, im = 0.f;
        #pragma unroll
        for (int i1 = 0; i1 < D1; ++i1) {
          const int i2 = (m - L) - (i1 - L1) + L2;   // unroll-time constant
          if (i2 >= 0 && i2 < D2) {                   // folds after unrolling
            const float c = CGTab<L, L1, L2>::tab.v[m][i1][i2];  // immediate
            if (c != 0.f) {
              re += c * (ar[i1] * br[i2] - ai[i1] * bi[i2]);
              im += c * (ar[i1] * bi[i2] + ai[i1] * br[i2]);
            }
          }
        }
        res[m] = make_float2(re, im);
      }

      if constexpr (D == 1) {
        // natural store is already 8B/lane contiguous — no staging needed
        po[tp] = res[0];
      } else {
        // WAR fence: previous iteration's ds_reads complete before overwrite
        asm volatile("s_waitcnt lgkmcnt(0)" ::: "memory");
        #pragma unroll
        for (int m = 0; m < D; ++m) swave[lane * D + m] = res[m];
        // RAW fence: writes complete before transposed reads
        asm volatile("s_waitcnt lgkmcnt(0)" ::: "memory");

        // wave tile = pairs [256j + 64wv, +64) x D, contiguous 512*D bytes
        const float4* s4  = (const float4*)swave;
        float4*       ow4 = (float4*)(po + (size_t)(256 * j + 64 * wv) * D);
        #pragma unroll
        for (int k = 0; k <= (D - 1) / 2; ++k) {        // 32*D float4 total
          const int f = lane + 64 * k;
          if (k < (D - 1) / 2 || lane < 32)             // last k: half wave
            ow4[f] = s4[f];
        }
      }
    }
  }
}

// ---------- compile-time BINARY dispatch over the 111 tuples ----------
template<int LO, int HI>
__device__ __forceinline__ void dispatch(int idx,
                                         const float* __restrict__ fs,
                                         float2* __restrict__ out,
                                         float2* __restrict__ stage) {
  if constexpr (HI - LO == 1) {
    constexpr Tup t = META.t[LO];
    tuple_impl<t.l, t.l1, t.l2>(fs, out, t.in1, t.in2, t.out_off, stage);
  } else {
    constexpr int MID = LO + (HI - LO) / 2;
    if (idx < MID) dispatch<LO, MID>(idx, fs, out, stage);
    else           dispatch<MID, HI>(idx, fs, out, stage);
  }
}

__global__ void __launch_bounds__(256)
cg_main(const float* __restrict__ fs, float2* __restrict__ out) {
  // 4 waves x 64 pairs x D<=11 float2 = 22.5 KB
  __shared__ float2 stage[4 * 64 * 11];
  dispatch<0, NT>(blockIdx.x, fs, out, stage);
}

extern "C" void kernel_launch(void* const* d_in, const int* in_sizes, int n_in,
                              void* d_out, int out_size, void* d_ws, size_t ws_size,
                              hipStream_t stream) {
  const float* fs = (const float*)d_in[0];
  float2* out = (float2*)d_out;
  (void)d_ws; (void)ws_size; (void)in_sizes; (void)n_in; (void)out_size;

  // x = tuple (consecutive blocks write contiguous output -> L2 locality),
  // y = batch-group of 4
  cg_main<<<dim3(NT, NBATCH / BPB), dim3(256), 0, stream>>>(fs, out);
}